// Round 10
// baseline (362.728 us; speedup 1.0000x reference)
//
#include <hip/hip_runtime.h>
#include <stdint.h>

// ---------- types ----------
typedef __bf16 bf16x8 __attribute__((ext_vector_type(8)));
typedef float  f32x4  __attribute__((ext_vector_type(4)));

__device__ __forceinline__ ushort f2bf(float f) {
    union { uint i; float f; } v; v.f = f;
    uint i = v.i;
    uint r = (i + 0x7fffu + ((i >> 16) & 1u)) >> 16;   // RNE
    return (ushort)r;
}
__device__ __forceinline__ ushort f2bf_t(float f) {   // truncate (cheap, f>=0 paths)
    union { uint i; float f; } v; v.f = f;
    return (ushort)(v.i >> 16);
}

// async global->LDS, 16 B per lane; lds base must be wave-uniform
__device__ __forceinline__ void gld16(const ushort* g, ushort* l) {
    __builtin_amdgcn_global_load_lds((const __attribute__((address_space(1))) uint*)g,
                                     (__attribute__((address_space(3))) uint*)l, 16, 0, 0);
}

// ---------- constants ----------
#define D_MODEL 1024
#define N_HEADS 16
#define HEAD_DIM 64
#define BATCH 2
#define SEQ 2048
#define M_ROWS (BATCH * SEQ)          // 4096
#define QKV_W  3072                   // 3*D_MODEL
#define SCALE_LOG2E 0.18033688f       // 0.125 * log2(e)
#define NBLK 256

// ---------- manual grid barrier (monotonic counter; agent-scope fences) ----------
// Safe without cooperative launch: grid=256 <= #CUs and every block fits any CU
// (8 waves, <=128 VGPR, 55.3KB LDS) => all blocks are resident unconditionally.
__device__ __forceinline__ void grid_barrier(int* cnt, int target, int tid) {
    __syncthreads();
    if (tid == 0) {
        __threadfence();                              // release: L2 writeback (agent)
        atomicAdd(cnt, 1);                            // device-scope by default
        while (__hip_atomic_load(cnt, __ATOMIC_ACQUIRE, __HIP_MEMORY_SCOPE_AGENT) < target)
            __builtin_amdgcn_s_sleep(2);
        __threadfence();                              // acquire: cache invalidate
    }
    __syncthreads();
}

// =====================================================================
// One kernel, 256 blocks x 512 threads:
// P0 prep -> P1 QKV GEMM -> P2 attention -> P3 out-proj
// =====================================================================
__global__ __launch_bounds__(512, 4) void fused_all(
    const float* __restrict__ x,    ushort* __restrict__ xb,
    const float* __restrict__ Wqkv, ushort* __restrict__ WqkvT,
    const float* __restrict__ Wo,   ushort* __restrict__ WoT,
    const float* __restrict__ bqkv, ushort* __restrict__ xqkv,
    ushort* __restrict__ aout, const float* __restrict__ bo,
    float* __restrict__ out, int* __restrict__ cnt)
{
    __shared__ ushort smem[27648] __attribute__((aligned(16)));   // 55,296 B

    const int tid  = threadIdx.x;
    const int bi   = blockIdx.x;
    const int lane = tid & 63;
    const int w    = tid >> 6;            // 0..7
    const int quad = lane >> 4;
    const int r15  = lane & 15;
    const int q8   = quad * 8;

    // ================= P0: cast x + transpose weights =================
    {
        // cast x: 1,048,576 float4 over 131,072 threads -> 8 each
#pragma unroll
        for (int k = 0; k < 8; ++k) {
            int i = k * 131072 + bi * 512 + tid;
            float4 v = ((const float4*)x)[i];
            ushort4 o;
            o.x = f2bf(v.x); o.y = f2bf(v.y); o.z = f2bf(v.z); o.w = f2bf(v.w);
            ((ushort4*)xb)[i] = o;
        }
        // transposes: 1024 jobs (768 Wqkv + 256 Wo), 4 per block
        float (*tile)[65] = (float(*)[65])(void*)smem;   // 64x65 f32 = 16,640 B
        for (int jj = 0; jj < 4; ++jj) {
            const int job = bi * 4 + jj;
            const float* in; ushort* outp; int Nd, bx, by;
            if (job < 768) { in = Wqkv; outp = WqkvT; Nd = QKV_W;   bx = job % 48;         by = job / 48; }
            else           { in = Wo;   outp = WoT;   Nd = D_MODEL; bx = (job - 768) & 15; by = (job - 768) >> 4; }
            const int k0 = by << 6, n0 = bx << 6;
            __syncthreads();                 // tile reuse guard
            {
                const int r = tid >> 3, c8 = (tid & 7) * 8;
                const float* src = in + (size_t)(k0 + r) * Nd + n0 + c8;
                float4 v0 = *(const float4*)src;
                float4 v1 = *(const float4*)(src + 4);
                tile[r][c8 + 0] = v0.x; tile[r][c8 + 1] = v0.y;
                tile[r][c8 + 2] = v0.z; tile[r][c8 + 3] = v0.w;
                tile[r][c8 + 4] = v1.x; tile[r][c8 + 5] = v1.y;
                tile[r][c8 + 6] = v1.z; tile[r][c8 + 7] = v1.w;
            }
            __syncthreads();
            {
                const int nn = tid & 63, k8 = (tid >> 6) * 8;
                ushort tmp[8] __attribute__((aligned(16)));
#pragma unroll
                for (int j = 0; j < 8; ++j) tmp[j] = f2bf(tile[k8 + j][nn]);
                *(uint4*)(outp + (size_t)(n0 + nn) * D_MODEL + k0 + k8) = *(const uint4*)tmp;
            }
        }
    }
    grid_barrier(cnt, NBLK, tid);

    // ================= P1: QKV GEMM -> xqkv [4096][3072] bf16 =================
    {
        ushort* As = smem;            // 128x32
        ushort* Bs = smem + 4096;     // 128x32
        const int wr = w >> 1, wc = w & 1;      // 4 row-groups x 2 col-groups
        const int crow = tid >> 2, ccol8 = (tid & 3) * 8;

        for (int ti = bi; ti < 768; ti += NBLK) {     // exactly 3 tiles/block
            const int bx = ti % 24, by = ti / 24;
            const int m0 = by * 128, n0 = bx * 128;
            f32x4 acc[2][4] = {};

            for (int k0 = 0; k0 < D_MODEL; k0 += 32) {
                gld16(xb    + (size_t)(m0 + crow) * D_MODEL + k0 + ccol8, As + w * 512);
                gld16(WqkvT + (size_t)(n0 + crow) * D_MODEL + k0 + ccol8, Bs + w * 512);
                __syncthreads();
                bf16x8 af[2], bfv[4];
#pragma unroll
                for (int mt = 0; mt < 2; ++mt)
                    af[mt] = *(const bf16x8*)&As[(wr * 32 + mt * 16 + r15) * 32 + q8];
#pragma unroll
                for (int nt = 0; nt < 4; ++nt)
                    bfv[nt] = *(const bf16x8*)&Bs[(wc * 64 + nt * 16 + r15) * 32 + q8];
#pragma unroll
                for (int mt = 0; mt < 2; ++mt)
#pragma unroll
                    for (int nt = 0; nt < 4; ++nt)
                        acc[mt][nt] = __builtin_amdgcn_mfma_f32_16x16x32_bf16(af[mt], bfv[nt], acc[mt][nt], 0, 0, 0);
                __syncthreads();
            }

            float bv[4];
#pragma unroll
            for (int nt = 0; nt < 4; ++nt) bv[nt] = bqkv[n0 + wc * 64 + nt * 16 + r15];
#pragma unroll
            for (int mt = 0; mt < 2; ++mt)
#pragma unroll
                for (int nt = 0; nt < 4; ++nt)
#pragma unroll
                    for (int r = 0; r < 4; ++r) {
                        int m = m0 + wr * 32 + mt * 16 + quad * 4 + r;
                        int n = n0 + wc * 64 + nt * 16 + r15;
                        xqkv[(size_t)m * QKV_W + n] = f2bf(acc[mt][nt][r] + bv[nt]);
                    }
        }
    }
    grid_barrier(cnt, 2 * NBLK, tid);

    // ================= P2: MFMA flash attention (r7-verified body) =================
    {
        ushort* KsA = smem;               // [2][64*72]
        ushort* VtA = smem + 9216;        // [2][64*72]
        ushort* Ps  = smem + 18432;       // [8][16*72]

        const int pp = bi >> 5;           // 0..7
        const int bh = bi & 31;
        const int b = bh >> 4, h = bh & 15;
        const int brow = b * SEQ;
        const int qcol = h * 64, kcol = D_MODEL + h * 64, vcol = 2 * D_MODEL + h * 64;

        const int srow = tid >> 3;            // 0..63
        const int scol = (tid & 7) * 8;       // 0..56
        const int kp = tid & 31;
        const int dg = tid >> 5;              // 0..15

        for (int it = 0; it < 2; ++it) {      // complementary pair: 34 tiles total
            const int p = (it == 0) ? (15 - pp) : pp;
            const int t1   = 2 * p + 2;
            const int q0   = p * 128;
            const int wq0  = q0 + w * 16;
            const int tdiag = t1 - 2 + (w >> 2);

            __syncthreads();                  // prev item's LDS readers done

            // Q fragments
            bf16x8 qf[2];
            {
                const ushort* qrow = xqkv + (size_t)(brow + wq0 + r15) * QKV_W + qcol;
                qf[0] = *(const bf16x8*)(qrow + q8);
                qf[1] = *(const bf16x8*)(qrow + 32 + q8);
            }

            f32x4 o_acc[4] = {};
            float l_lane[4] = {0.f, 0.f, 0.f, 0.f};

            uint4 kr; uint2 va, vb;
            // load tile 0 -> regs
            {
                const ushort* kpt = xqkv + (size_t)(brow + srow) * QKV_W + kcol + scol;
                kr = *(const uint4*)kpt;
                const ushort* vpt = xqkv + (size_t)(brow + 2 * kp) * QKV_W + vcol + dg * 4;
                va = *(const uint2*)vpt; vb = *(const uint2*)(vpt + QKV_W);
            }
            // write buf0
            {
                *(uint4*)&KsA[srow * 72 + scol] = kr;
                const ushort* ap = (const ushort*)&va;
                const ushort* bp = (const ushort*)&vb;
                uint* vt32 = (uint*)VtA;
#pragma unroll
                for (int j = 0; j < 4; ++j)
                    vt32[(dg * 4 + j) * 36 + kp] = (uint)ap[j] | ((uint)bp[j] << 16);
            }
            // load tile 1 -> regs
            if (1 < t1) {
                const ushort* kpt = xqkv + (size_t)(brow + 64 + srow) * QKV_W + kcol + scol;
                kr = *(const uint4*)kpt;
                const ushort* vpt = xqkv + (size_t)(brow + 64 + 2 * kp) * QKV_W + vcol + dg * 4;
                va = *(const uint2*)vpt; vb = *(const uint2*)(vpt + QKV_W);
            }

            for (int t = 0; t < t1; ++t) {
                __syncthreads();
                if (t + 1 < t1) {
                    const int b1 = (t + 1) & 1;
                    ushort* ks = KsA + b1 * 4608;
                    *(uint4*)&ks[srow * 72 + scol] = kr;
                    const ushort* ap = (const ushort*)&va;
                    const ushort* bp = (const ushort*)&vb;
                    uint* vt32 = (uint*)(VtA + b1 * 4608);
#pragma unroll
                    for (int j = 0; j < 4; ++j)
                        vt32[(dg * 4 + j) * 36 + kp] = (uint)ap[j] | ((uint)bp[j] << 16);
                }
                if (t + 2 < t1) {
                    const int key2 = (t + 2) << 6;
                    const ushort* kpt = xqkv + (size_t)(brow + key2 + srow) * QKV_W + kcol + scol;
                    kr = *(const uint4*)kpt;
                    const ushort* vpt = xqkv + (size_t)(brow + key2 + 2 * kp) * QKV_W + vcol + dg * 4;
                    va = *(const uint2*)vpt; vb = *(const uint2*)(vpt + QKV_W);
                }

                const int ntmax = (t < tdiag) ? 4 : ((t == tdiag) ? (w & 3) + 1 : 0);
                if (ntmax == 0) continue;

                const ushort* KsB = KsA + (t & 1) * 4608;
                const ushort* VtB = VtA + (t & 1) * 4608;
                const bool diag = (t == tdiag);

                // S = Q K^T
                f32x4 s_acc[4];
#pragma unroll
                for (int nt = 0; nt < 4; ++nt) {
                    if (nt >= ntmax) continue;
                    f32x4 z = {};
#pragma unroll
                    for (int ks = 0; ks < 2; ++ks) {
                        bf16x8 kf = *(const bf16x8*)&KsB[(nt * 16 + r15) * 72 + ks * 32 + q8];
                        z = __builtin_amdgcn_mfma_f32_16x16x32_bf16(qf[ks], kf, z, 0, 0, 0);
                    }
                    s_acc[nt] = z;
                }
                // p = exp2(s*scale); mask only the diagonal strip
#pragma unroll
                for (int nt = 0; nt < 4; ++nt) {
                    if (nt >= ntmax) continue;
#pragma unroll
                    for (int j = 0; j < 4; ++j) {
                        float e = exp2f(s_acc[nt][j] * SCALE_LOG2E);
                        if (diag && nt == (w & 3) && r15 > quad * 4 + j) e = 0.f;
                        s_acc[nt][j] = e;
                        l_lane[j] += e;
                    }
                }
                // P: C-layout -> A-layout via per-wave LDS round trip (stride 72)
                ushort* pb = Ps + w * (16 * 72);
#pragma unroll
                for (int nt = 0; nt < 4; ++nt)
#pragma unroll
                    for (int j = 0; j < 4; ++j)
                        pb[(quad * 4 + j) * 72 + nt * 16 + r15] =
                            (nt < ntmax) ? f2bf_t(s_acc[nt][j]) : (ushort)0;
                bf16x8 pf0 = *(const bf16x8*)&pb[r15 * 72 + q8];
                bf16x8 pf1 = *(const bf16x8*)&pb[r15 * 72 + 32 + q8];

                // O += P V
#pragma unroll
                for (int nt = 0; nt < 4; ++nt) {
                    const int d0 = nt * 16 + r15;
                    bf16x8 vf0 = *(const bf16x8*)&VtB[d0 * 72 + q8];
                    bf16x8 vf1 = *(const bf16x8*)&VtB[d0 * 72 + 32 + q8];
                    o_acc[nt] = __builtin_amdgcn_mfma_f32_16x16x32_bf16(pf0, vf0, o_acc[nt], 0, 0, 0);
                    o_acc[nt] = __builtin_amdgcn_mfma_f32_16x16x32_bf16(pf1, vf1, o_acc[nt], 0, 0, 0);
                }
            }

            // epilogue: reduce l over the 16 lanes of each quad, store bf16
            float lsum[4];
#pragma unroll
            for (int j = 0; j < 4; ++j) {
                float l = l_lane[j];
                l += __shfl_xor(l, 1);
                l += __shfl_xor(l, 2);
                l += __shfl_xor(l, 4);
                l += __shfl_xor(l, 8);
                lsum[j] = l;
            }
#pragma unroll
            for (int nt = 0; nt < 4; ++nt)
#pragma unroll
                for (int j = 0; j < 4; ++j) {
                    int qg = wq0 + quad * 4 + j;
                    float v = o_acc[nt][j] / lsum[j];
                    aout[(size_t)(brow + qg) * D_MODEL + h * 64 + nt * 16 + r15] = f2bf(v);
                }
        }
    }
    grid_barrier(cnt, 3 * NBLK, tid);

    // ================= P3: out-projection GEMM 64x128 -> out f32 =================
    {
        ushort* As = smem;            // 64x32
        ushort* Bs = smem + 2048;     // 128x32
        const int wr = w >> 1;        // 0..3, 16-row groups
        const int wc = w & 1;         // 0..1, 64-col groups
        const int crow = tid >> 2, ccol8 = (tid & 3) * 8;         // B chunks (512)
        const int arow = (tid & 255) >> 2, acol8 = (tid & 3) * 8; // A chunks (waves 0-3)

        __syncthreads();              // P2 LDS readers done (barrier above covers, belt)

        for (int ti = bi * 2; ti < bi * 2 + 2; ++ti) {  // 2 tiles/block
            const int by = ti >> 3, bx = ti & 7;
            const int m0 = by * 64, n0 = bx * 128;
            f32x4 acc[4] = {};

            for (int k0 = 0; k0 < D_MODEL; k0 += 32) {
                if (w < 4)
                    gld16(aout + (size_t)(m0 + arow) * D_MODEL + k0 + acol8, As + w * 512);
                gld16(WoT + (size_t)(n0 + crow) * D_MODEL + k0 + ccol8, Bs + w * 512);
                __syncthreads();
                bf16x8 af = *(const bf16x8*)&As[(wr * 16 + r15) * 32 + q8];
                bf16x8 bfv[4];
#pragma unroll
                for (int nt = 0; nt < 4; ++nt)
                    bfv[nt] = *(const bf16x8*)&Bs[(wc * 64 + nt * 16 + r15) * 32 + q8];
#pragma unroll
                for (int nt = 0; nt < 4; ++nt)
                    acc[nt] = __builtin_amdgcn_mfma_f32_16x16x32_bf16(af, bfv[nt], acc[nt], 0, 0, 0);
                __syncthreads();
            }

#pragma unroll
            for (int nt = 0; nt < 4; ++nt) {
                float bvn = bo[n0 + wc * 64 + nt * 16 + r15];
#pragma unroll
                for (int r = 0; r < 4; ++r) {
                    int m = m0 + wr * 16 + quad * 4 + r;
                    int n = n0 + wc * 64 + nt * 16 + r15;
                    out[(size_t)m * D_MODEL + n] = acc[nt][r] + bvn;
                }
            }
        }
    }
}

// ---------- launch ----------
extern "C" void kernel_launch(void* const* d_in, const int* in_sizes, int n_in,
                              void* d_out, int out_size, void* d_ws, size_t ws_size,
                              hipStream_t stream)
{
    const float* x    = (const float*)d_in[0];
    // d_in[1] = causal mask — applied analytically, ignored
    const float* Wqkv = (const float*)d_in[2];
    const float* bqkv = (const float*)d_in[3];
    const float* Wo   = (const float*)d_in[4];
    const float* bo   = (const float*)d_in[5];
    float* out = (float*)d_out;

    char* ws = (char*)d_ws;
    size_t off = 0;
    ushort* xb    = (ushort*)(ws + off); off += (size_t)M_ROWS * D_MODEL * 2;   // 8 MB
    ushort* WqkvT = (ushort*)(ws + off); off += (size_t)QKV_W * D_MODEL * 2;    // 6 MB
    ushort* WoT   = (ushort*)(ws + off); off += (size_t)D_MODEL * D_MODEL * 2;  // 2 MB
    ushort* xqkv  = (ushort*)(ws + off); off += (size_t)M_ROWS * QKV_W * 2;     // 24 MB
    ushort* aout  = (ushort*)(ws + off); off += (size_t)M_ROWS * D_MODEL * 2;   // 8 MB
    int* cnt      = (int*)(ws + off);    off += 256;

    hipMemsetAsync(cnt, 0, 4, stream);

    fused_all<<<NBLK, 512, 0, stream>>>(x, xb, Wqkv, WqkvT, Wo, WoT,
                                        bqkv, xqkv, aout, bo, out, cnt);
}